// Round 1
// baseline (435.463 us; speedup 1.0000x reference)
//
#include <hip/hip_runtime.h>

// ---------------------------------------------------------------------------
// MLA (LoraQKV) pipeline for MI355X, bf16 MFMA everywhere.
// Stages:
//   1) cvt_pad: f32->bf16 weight/activation converts (W1 = [q_a_w; kv_a_w; 0pad])
//   2) gemm_bt: C1 = hs @ W1^T            (2048 x 2048 x 2048)
//   3) rmsnorm_rope: q_lat_n, ckv_n (bf16), k_rope (RoPE'd bf16)
//   4) gemm_bt: Qf  = q_lat_n @ q_b_w^T   (2048 x 4096 x 1024)
//      gemm_bt: KVf = ckv_n  @ kv_b_w^T   (2048 x 4096 x 896)
//   5) q_post: RoPE(q_rope), *SCALE, ->bf16 Qb   [s][h*128+idx]
//      kv_post: Kb=[k_nope|k_rope] per head, Vt = V^T per head (bf16)
//   6) flash_attn: causal online-softmax, 64 q-rows/block, 64-key tiles -> Ao
//   7) gemm_bt: out = Ao @ o_w^T -> f32 d_out
// Workspace overlays (MB offsets): see kernel_launch.
// ---------------------------------------------------------------------------

typedef __attribute__((ext_vector_type(8))) __bf16 bf16x8;
typedef __attribute__((ext_vector_type(4))) float f32x4;

__device__ __forceinline__ unsigned short f2bf(float f) {
  unsigned int x = __builtin_bit_cast(unsigned int, f);
  x += 0x7fffu + ((x >> 16) & 1u);
  return (unsigned short)(x >> 16);
}
__device__ __forceinline__ float bf2f(unsigned short u) {
  unsigned int x = ((unsigned int)u) << 16;
  return __builtin_bit_cast(float, x);
}
__device__ __forceinline__ void gload_lds16(const void* g, void* l) {
  __builtin_amdgcn_global_load_lds(
      (const __attribute__((address_space(1))) void*)g,
      (__attribute__((address_space(3))) void*)l, 16, 0, 0);
}

// ---------------- converts ----------------
__global__ __launch_bounds__(256) void cvt_pad(const float* __restrict__ src,
                                               unsigned short* __restrict__ dst,
                                               size_t n_src, size_t n_tot) {
  size_t i = ((size_t)blockIdx.x * 256 + threadIdx.x) * 4;
  if (i >= n_tot) return;
  unsigned short o0 = 0, o1 = 0, o2 = 0, o3 = 0;
  if (i < n_src) {
    float4 v = *reinterpret_cast<const float4*>(src + i);
    o0 = f2bf(v.x); o1 = f2bf(v.y); o2 = f2bf(v.z); o3 = f2bf(v.w);
  }
  *reinterpret_cast<ushort4*>(dst + i) = make_ushort4(o0, o1, o2, o3);
}

// ---------------- GEMM: C[M,N] = A[M,K] @ B[N,K]^T (bf16 in, f32 out) -------
// 128x128 tile, BK=64, 256 threads (4 waves, 2x2), 4x4 16x16x32 frags/wave.
__global__ __launch_bounds__(256) void gemm_bt(const unsigned short* __restrict__ A,
                                               const unsigned short* __restrict__ B,
                                               float* __restrict__ C,
                                               int M, int N, int K) {
  __shared__ unsigned short lA[128 * 64];
  __shared__ unsigned short lB[128 * 64];
  const int tid = threadIdx.x, lane = tid & 63, wv = tid >> 6;
  const int wr = wv >> 1, wc = wv & 1;
  const int bm = blockIdx.y * 128, bn = blockIdx.x * 128;

  f32x4 acc[4][4] = {};

  const int rs = wv * 8 + (lane >> 3);   // staging row within 32-row group
  const int cs = (lane & 7) * 8;         // staging col (elements)

  for (int k0 = 0; k0 < K; k0 += 64) {
#pragma unroll
    for (int i = 0; i < 4; ++i) {
      gload_lds16(A + (size_t)(bm + i * 32 + rs) * K + k0 + cs, &lA[(i * 32 + wv * 8) * 64]);
      gload_lds16(B + (size_t)(bn + i * 32 + rs) * K + k0 + cs, &lB[(i * 32 + wv * 8) * 64]);
    }
    __syncthreads();
#pragma unroll
    for (int ks = 0; ks < 2; ++ks) {
      bf16x8 af[4], bfr[4];
#pragma unroll
      for (int m = 0; m < 4; ++m)
        af[m] = *reinterpret_cast<const bf16x8*>(
            &lA[(wr * 64 + m * 16 + (lane & 15)) * 64 + ks * 32 + (lane >> 4) * 8]);
#pragma unroll
      for (int n = 0; n < 4; ++n)
        bfr[n] = *reinterpret_cast<const bf16x8*>(
            &lB[(wc * 64 + n * 16 + (lane & 15)) * 64 + ks * 32 + (lane >> 4) * 8]);
#pragma unroll
      for (int m = 0; m < 4; ++m)
#pragma unroll
        for (int n = 0; n < 4; ++n)
          acc[m][n] = __builtin_amdgcn_mfma_f32_16x16x32_bf16(af[m], bfr[n], acc[m][n], 0, 0, 0);
    }
    __syncthreads();
  }

  const int r0 = bm + wr * 64, c0 = bn + wc * 64;
#pragma unroll
  for (int m = 0; m < 4; ++m)
#pragma unroll
    for (int n = 0; n < 4; ++n)
#pragma unroll
      for (int r = 0; r < 4; ++r)
        C[(size_t)(r0 + m * 16 + (lane >> 4) * 4 + r) * N + c0 + n * 16 + (lane & 15)] =
            acc[m][n][r];
}

// ---------------- RMSNorm(q_lat), RMSNorm(c_kv), RoPE(k_rope) ---------------
__global__ __launch_bounds__(256) void rmsnorm_rope(const float* __restrict__ C1,
                                                    const float* __restrict__ qw,
                                                    const float* __restrict__ kvw,
                                                    const float* __restrict__ cosp,
                                                    const float* __restrict__ sinp,
                                                    unsigned short* __restrict__ qn,
                                                    unsigned short* __restrict__ ckvn,
                                                    unsigned short* __restrict__ kr) {
  const int s = blockIdx.x, tid = threadIdx.x;
  const float* row = C1 + (size_t)s * 2048;
  __shared__ float red[4];

  // q_lat: 1024
  float ss = 0.f;
  for (int c = tid; c < 1024; c += 256) { float v = row[c]; ss += v * v; }
  ss += __shfl_xor(ss, 32); ss += __shfl_xor(ss, 16); ss += __shfl_xor(ss, 8);
  ss += __shfl_xor(ss, 4);  ss += __shfl_xor(ss, 2);  ss += __shfl_xor(ss, 1);
  if ((tid & 63) == 0) red[tid >> 6] = ss;
  __syncthreads();
  float rs = rsqrtf((red[0] + red[1] + red[2] + red[3]) * (1.f / 1024.f) + 1e-6f);
  for (int c = tid; c < 1024; c += 256)
    qn[(size_t)s * 1024 + c] = f2bf(row[c] * rs * qw[c]);

  // c_kv: 896
  ss = 0.f;
  for (int c = tid; c < 896; c += 256) { float v = row[1024 + c]; ss += v * v; }
  ss += __shfl_xor(ss, 32); ss += __shfl_xor(ss, 16); ss += __shfl_xor(ss, 8);
  ss += __shfl_xor(ss, 4);  ss += __shfl_xor(ss, 2);  ss += __shfl_xor(ss, 1);
  __syncthreads();                 // protect red from round-1 readers
  if ((tid & 63) == 0) red[tid >> 6] = ss;
  __syncthreads();
  rs = rsqrtf((red[0] + red[1] + red[2] + red[3]) * (1.f / 896.f) + 1e-6f);
  for (int c = tid; c < 896; c += 256)
    ckvn[(size_t)s * 896 + c] = f2bf(row[1024 + c] * rs * kvw[c]);

  // k_rope: cols 1920..1983, RoPE
  if (tid < 64) {
    int d = tid;
    float x = row[1920 + d];
    float part = (d < 32) ? -row[1920 + d + 32] : row[1920 + d - 32];
    float v = x * cosp[(size_t)s * 64 + d] + part * sinp[(size_t)s * 64 + d];
    kr[(size_t)s * 64 + d] = f2bf(v);
  }
}

// ---------------- Q post: RoPE + SCALE -> bf16 ------------------------------
__global__ __launch_bounds__(256) void q_post(const float* __restrict__ Qf,
                                              const float* __restrict__ cosp,
                                              const float* __restrict__ sinp,
                                              unsigned short* __restrict__ Qb) {
  size_t idx = (size_t)blockIdx.x * 256 + threadIdx.x;   // grid covers 2048*4096
  int s = (int)(idx >> 12);
  int within = (int)(idx & 127);
  float v;
  if (within < 64) {
    v = Qf[idx];
  } else {
    int d = within - 64;
    float x = Qf[idx];
    float part = (d < 32) ? -Qf[idx + 32] : Qf[idx - 32];
    v = x * cosp[(size_t)s * 64 + d] + part * sinp[(size_t)s * 64 + d];
  }
  Qb[idx] = f2bf(v * 0.125f);   // SCALE = HD^-0.5
}

// ---------------- KV post: Kb=[k_nope|k_rope], Vt = V^T ---------------------
__global__ __launch_bounds__(256) void kv_post(const float* __restrict__ KVf,
                                               const unsigned short* __restrict__ kr,
                                               unsigned short* __restrict__ Kb,
                                               unsigned short* __restrict__ Vt) {
  __shared__ float lT[64 * 65];
  const int s0 = blockIdx.x * 64, h = blockIdx.y, tid = threadIdx.x;
  for (int idx = tid; idx < 4096; idx += 256) {
    int r = idx >> 6, c = idx & 63;
    size_t base = (size_t)(s0 + r) * 4096 + h * 128;
    Kb[base + c] = f2bf(KVf[base + c]);
    Kb[base + 64 + c] = kr[(size_t)(s0 + r) * 64 + c];
    lT[r * 65 + c] = KVf[base + 64 + c];
  }
  __syncthreads();
  for (int idx = tid; idx < 4096; idx += 256) {
    int d = idx >> 6, c = idx & 63;
    Vt[((size_t)h * 64 + d) * 2048 + s0 + c] = f2bf(lT[c * 65 + d]);
  }
}

// ---------------- flash attention (causal) ----------------------------------
// grid (S/64, NH), 256 threads = 4 waves; wave w owns q rows [q0+16w, q0+16w+16)
__global__ __launch_bounds__(256) void flash_attn(const unsigned short* __restrict__ Qb,
                                                  const unsigned short* __restrict__ Kb,
                                                  const unsigned short* __restrict__ Vt,
                                                  unsigned short* __restrict__ Ao) {
  __shared__ unsigned short lK[64 * 128];
  __shared__ unsigned short lV[64 * 64];
  __shared__ unsigned short lP[4 * 16 * 64];
  const int tid = threadIdx.x, lane = tid & 63, wv = tid >> 6;
  const int q0 = blockIdx.x * 64, h = blockIdx.y;

  bf16x8 qf[4];
  {
    const unsigned short* qrow = Qb + (size_t)(q0 + wv * 16 + (lane & 15)) * 4096 + h * 128;
#pragma unroll
    for (int ks = 0; ks < 4; ++ks)
      qf[ks] = *reinterpret_cast<const bf16x8*>(qrow + ks * 32 + (lane >> 4) * 8);
  }

  f32x4 o_acc[4] = {};
  float mrow[4] = {-1e30f, -1e30f, -1e30f, -1e30f};
  float lrow[4] = {};

  for (int j0 = 0; j0 <= q0; j0 += 64) {
    {
      const int rk = wv * 4 + (lane >> 4), ck = (lane & 15) * 8;
#pragma unroll
      for (int i = 0; i < 4; ++i)
        gload_lds16(Kb + (size_t)(j0 + i * 16 + rk) * 4096 + h * 128 + ck,
                    &lK[(i * 16 + wv * 4) * 128]);
      const int rv = wv * 8 + (lane >> 3), cv = (lane & 7) * 8;
#pragma unroll
      for (int i = 0; i < 2; ++i)
        gload_lds16(Vt + ((size_t)h * 64 + i * 32 + rv) * 2048 + j0 + cv,
                    &lV[(i * 32 + wv * 8) * 64]);
    }
    __syncthreads();

    f32x4 s_acc[4] = {};
#pragma unroll
    for (int n = 0; n < 4; ++n)
#pragma unroll
      for (int ks = 0; ks < 4; ++ks) {
        bf16x8 kf = *reinterpret_cast<const bf16x8*>(
            &lK[(n * 16 + (lane & 15)) * 128 + ks * 32 + (lane >> 4) * 8]);
        s_acc[n] = __builtin_amdgcn_mfma_f32_16x16x32_bf16(qf[ks], kf, s_acc[n], 0, 0, 0);
      }

    if (j0 == q0) {  // diagonal block: causal mask
#pragma unroll
      for (int n = 0; n < 4; ++n)
#pragma unroll
        for (int r = 0; r < 4; ++r) {
          int qr = q0 + wv * 16 + (lane >> 4) * 4 + r;
          int kc = j0 + n * 16 + (lane & 15);
          if (kc > qr) s_acc[n][r] = -1e30f;
        }
    }

#pragma unroll
    for (int r = 0; r < 4; ++r) {
      float mx = fmaxf(fmaxf(s_acc[0][r], s_acc[1][r]), fmaxf(s_acc[2][r], s_acc[3][r]));
      mx = fmaxf(mx, __shfl_xor(mx, 1));
      mx = fmaxf(mx, __shfl_xor(mx, 2));
      mx = fmaxf(mx, __shfl_xor(mx, 4));
      mx = fmaxf(mx, __shfl_xor(mx, 8));
      float mn = fmaxf(mrow[r], mx);
      float sf = __expf(mrow[r] - mn);
      mrow[r] = mn;
      lrow[r] *= sf;
      o_acc[0][r] *= sf; o_acc[1][r] *= sf; o_acc[2][r] *= sf; o_acc[3][r] *= sf;
      float ps = 0.f;
#pragma unroll
      for (int n = 0; n < 4; ++n) {
        float p = __expf(s_acc[n][r] - mn);
        ps += p;
        lP[(wv * 16 + (lane >> 4) * 4 + r) * 64 + n * 16 + (lane & 15)] = f2bf(p);
      }
      ps += __shfl_xor(ps, 1); ps += __shfl_xor(ps, 2);
      ps += __shfl_xor(ps, 4); ps += __shfl_xor(ps, 8);
      lrow[r] += ps;
    }

#pragma unroll
    for (int ks = 0; ks < 2; ++ks) {
      bf16x8 pa = *reinterpret_cast<const bf16x8*>(
          &lP[(wv * 16 + (lane & 15)) * 64 + ks * 32 + (lane >> 4) * 8]);
#pragma unroll
      for (int n = 0; n < 4; ++n) {
        bf16x8 vb = *reinterpret_cast<const bf16x8*>(
            &lV[(n * 16 + (lane & 15)) * 64 + ks * 32 + (lane >> 4) * 8]);
        o_acc[n] = __builtin_amdgcn_mfma_f32_16x16x32_bf16(pa, vb, o_acc[n], 0, 0, 0);
      }
    }
    __syncthreads();
  }

#pragma unroll
  for (int n = 0; n < 4; ++n)
#pragma unroll
    for (int r = 0; r < 4; ++r) {
      float o = o_acc[n][r] / lrow[r];
      Ao[(size_t)(q0 + wv * 16 + (lane >> 4) * 4 + r) * 2048 + h * 64 + n * 16 + (lane & 15)] =
          f2bf(o);
    }
}

// ---------------------------------------------------------------------------
extern "C" void kernel_launch(void* const* d_in, const int* in_sizes, int n_in,
                              void* d_out, int out_size, void* d_ws, size_t ws_size,
                              hipStream_t stream) {
  const float* hs   = (const float*)d_in[0];
  const float* cosp = (const float*)d_in[1];
  const float* sinp = (const float*)d_in[2];
  const float* qaw  = (const float*)d_in[3];
  const float* qaln = (const float*)d_in[4];
  const float* qbwf = (const float*)d_in[5];
  const float* kvaw = (const float*)d_in[6];
  const float* kvln = (const float*)d_in[7];
  const float* kvbwf= (const float*)d_in[8];
  const float* owf  = (const float*)d_in[9];
  float* out = (float*)d_out;
  char* ws = (char*)d_ws;
  const size_t MB = 1u << 20;

  // overlay map (lifetimes commented in header)
  unsigned short* W1b  = (unsigned short*)(ws + 0);        // 8 MB   [dead after gemm1]
  unsigned short* Ao   = (unsigned short*)(ws + 0);        // 8 MB   (flash out)
  unsigned short* qbw  = (unsigned short*)(ws + 8 * MB);   // 8 MB   [dead after gemm2a]
  unsigned short* Vt   = (unsigned short*)(ws + 8 * MB);   // 8 MB   (kv_post out)
  unsigned short* kvbw = (unsigned short*)(ws + 16 * MB);  // 7 MB
  unsigned short* owb  = (unsigned short*)(ws + 23 * MB);  // 8 MB
  unsigned short* hsb  = (unsigned short*)(ws + 31 * MB);  // 8 MB   [dead after gemm1]
  unsigned short* Qb   = (unsigned short*)(ws + 31 * MB);  // 16 MB  (q_post out)
  float*          C1   = (float*)(ws + 39 * MB);           // 16 MB  [dead after rmsnorm]
  unsigned short* Kb   = (unsigned short*)(ws + 47 * MB);  // 16 MB  (kv_post out)
  unsigned short* qln  = (unsigned short*)(ws + 55 * MB);  // 4 MB   [dead after gemm2a]
  unsigned short* ckvn = (unsigned short*)(ws + 59 * MB);  // 3.5 MB [dead after gemm2b]
  unsigned short* kr   = (unsigned short*)(ws + 63 * MB);  // 0.25 MB
  float*          Qf   = (float*)(ws + 64 * MB);           // 32 MB
  float*          KVf  = (float*)(ws + 96 * MB);           // 32 MB
  (void)ws_size; (void)in_sizes; (void)n_in; (void)out_size;

  auto cgrid = [](size_t n) { return dim3((unsigned)((n / 4 + 255) / 256)); };

  // 1) converts
  cvt_pad<<<cgrid((size_t)1024 * 2048), 256, 0, stream>>>(qaw, W1b, (size_t)1024 * 2048, (size_t)1024 * 2048);
  cvt_pad<<<cgrid((size_t)1024 * 2048), 256, 0, stream>>>(kvaw, W1b + (size_t)1024 * 2048, (size_t)960 * 2048, (size_t)1024 * 2048);
  cvt_pad<<<cgrid((size_t)2048 * 2048), 256, 0, stream>>>(hs, hsb, (size_t)2048 * 2048, (size_t)2048 * 2048);
  cvt_pad<<<cgrid((size_t)4096 * 1024), 256, 0, stream>>>(qbwf, qbw, (size_t)4096 * 1024, (size_t)4096 * 1024);
  cvt_pad<<<cgrid((size_t)4096 * 896), 256, 0, stream>>>(kvbwf, kvbw, (size_t)4096 * 896, (size_t)4096 * 896);
  cvt_pad<<<cgrid((size_t)2048 * 2048), 256, 0, stream>>>(owf, owb, (size_t)2048 * 2048, (size_t)2048 * 2048);

  // 2) C1 = hs @ W1^T
  gemm_bt<<<dim3(16, 16), 256, 0, stream>>>(hsb, W1b, C1, 2048, 2048, 2048);

  // 3) rmsnorms + k_rope RoPE
  rmsnorm_rope<<<2048, 256, 0, stream>>>(C1, qaln, kvln, cosp, sinp, qln, ckvn, kr);

  // 4) big projections
  gemm_bt<<<dim3(32, 16), 256, 0, stream>>>(qln, qbw, Qf, 2048, 4096, 1024);
  gemm_bt<<<dim3(32, 16), 256, 0, stream>>>(ckvn, kvbw, KVf, 2048, 4096, 896);

  // 5) posts
  q_post<<<dim3((unsigned)(((size_t)2048 * 4096) / 256)), 256, 0, stream>>>(Qf, cosp, sinp, Qb);
  kv_post<<<dim3(32, 32), 256, 0, stream>>>(KVf, kr, Kb, Vt);

  // 6) attention
  flash_attn<<<dim3(32, 32), 256, 0, stream>>>(Qb, Kb, Vt, Ao);

  // 7) output projection -> f32 out
  gemm_bt<<<dim3(16, 16), 256, 0, stream>>>(Ao, owb, out, 2048, 2048, 2048);
}

// Round 2
// 290.771 us; speedup vs baseline: 1.4976x; 1.4976x over previous
//
#include <hip/hip_runtime.h>

// ---------------------------------------------------------------------------
// MLA (LoraQKV) pipeline for MI355X, bf16 MFMA everywhere.
//   1) cvt_pad converts; 2) gemm_bt C1 = hs@W1^T; 3) rmsnorm_rope;
//   4) gemm_bt Qf/KVf; 5) q_post/kv_post; 6) flash_attn (causal, swizzled LDS);
//   7) gemm_bt out = Ao@o_w^T.
// R1: flash_attn LDS XOR-swizzle (lK/lV via pre-swizzled gload_lds source,
//     lP padded to 72), LPT dispatch order (heavy q-blocks first), setprio.
// ---------------------------------------------------------------------------

typedef __attribute__((ext_vector_type(8))) __bf16 bf16x8;
typedef __attribute__((ext_vector_type(4))) float f32x4;

__device__ __forceinline__ unsigned short f2bf(float f) {
  unsigned int x = __builtin_bit_cast(unsigned int, f);
  x += 0x7fffu + ((x >> 16) & 1u);
  return (unsigned short)(x >> 16);
}
__device__ __forceinline__ void gload_lds16(const void* g, void* l) {
  __builtin_amdgcn_global_load_lds(
      (const __attribute__((address_space(1))) void*)g,
      (__attribute__((address_space(3))) void*)l, 16, 0, 0);
}

// ---------------- converts ----------------
__global__ __launch_bounds__(256) void cvt_pad(const float* __restrict__ src,
                                               unsigned short* __restrict__ dst,
                                               size_t n_src, size_t n_tot) {
  size_t i = ((size_t)blockIdx.x * 256 + threadIdx.x) * 4;
  if (i >= n_tot) return;
  unsigned short o0 = 0, o1 = 0, o2 = 0, o3 = 0;
  if (i < n_src) {
    float4 v = *reinterpret_cast<const float4*>(src + i);
    o0 = f2bf(v.x); o1 = f2bf(v.y); o2 = f2bf(v.z); o3 = f2bf(v.w);
  }
  *reinterpret_cast<ushort4*>(dst + i) = make_ushort4(o0, o1, o2, o3);
}

// ---------------- GEMM: C[M,N] = A[M,K] @ B[N,K]^T (bf16 in, f32 out) -------
__global__ __launch_bounds__(256) void gemm_bt(const unsigned short* __restrict__ A,
                                               const unsigned short* __restrict__ B,
                                               float* __restrict__ C,
                                               int M, int N, int K) {
  __shared__ unsigned short lA[128 * 64];
  __shared__ unsigned short lB[128 * 64];
  const int tid = threadIdx.x, lane = tid & 63, wv = tid >> 6;
  const int wr = wv >> 1, wc = wv & 1;
  const int bm = blockIdx.y * 128, bn = blockIdx.x * 128;

  f32x4 acc[4][4] = {};

  const int rs = wv * 8 + (lane >> 3);
  const int cs = (lane & 7) * 8;

  for (int k0 = 0; k0 < K; k0 += 64) {
#pragma unroll
    for (int i = 0; i < 4; ++i) {
      gload_lds16(A + (size_t)(bm + i * 32 + rs) * K + k0 + cs, &lA[(i * 32 + wv * 8) * 64]);
      gload_lds16(B + (size_t)(bn + i * 32 + rs) * K + k0 + cs, &lB[(i * 32 + wv * 8) * 64]);
    }
    __syncthreads();
#pragma unroll
    for (int ks = 0; ks < 2; ++ks) {
      bf16x8 af[4], bfr[4];
#pragma unroll
      for (int m = 0; m < 4; ++m)
        af[m] = *reinterpret_cast<const bf16x8*>(
            &lA[(wr * 64 + m * 16 + (lane & 15)) * 64 + ks * 32 + (lane >> 4) * 8]);
#pragma unroll
      for (int n = 0; n < 4; ++n)
        bfr[n] = *reinterpret_cast<const bf16x8*>(
            &lB[(wc * 64 + n * 16 + (lane & 15)) * 64 + ks * 32 + (lane >> 4) * 8]);
#pragma unroll
      for (int m = 0; m < 4; ++m)
#pragma unroll
        for (int n = 0; n < 4; ++n)
          acc[m][n] = __builtin_amdgcn_mfma_f32_16x16x32_bf16(af[m], bfr[n], acc[m][n], 0, 0, 0);
    }
    __syncthreads();
  }

  const int r0 = bm + wr * 64, c0 = bn + wc * 64;
#pragma unroll
  for (int m = 0; m < 4; ++m)
#pragma unroll
    for (int n = 0; n < 4; ++n)
#pragma unroll
      for (int r = 0; r < 4; ++r)
        C[(size_t)(r0 + m * 16 + (lane >> 4) * 4 + r) * N + c0 + n * 16 + (lane & 15)] =
            acc[m][n][r];
}

// ---------------- RMSNorm(q_lat), RMSNorm(c_kv), RoPE(k_rope) ---------------
__global__ __launch_bounds__(256) void rmsnorm_rope(const float* __restrict__ C1,
                                                    const float* __restrict__ qw,
                                                    const float* __restrict__ kvw,
                                                    const float* __restrict__ cosp,
                                                    const float* __restrict__ sinp,
                                                    unsigned short* __restrict__ qn,
                                                    unsigned short* __restrict__ ckvn,
                                                    unsigned short* __restrict__ kr) {
  const int s = blockIdx.x, tid = threadIdx.x;
  const float* row = C1 + (size_t)s * 2048;
  __shared__ float red[4];

  float ss = 0.f;
  for (int c = tid; c < 1024; c += 256) { float v = row[c]; ss += v * v; }
  ss += __shfl_xor(ss, 32); ss += __shfl_xor(ss, 16); ss += __shfl_xor(ss, 8);
  ss += __shfl_xor(ss, 4);  ss += __shfl_xor(ss, 2);  ss += __shfl_xor(ss, 1);
  if ((tid & 63) == 0) red[tid >> 6] = ss;
  __syncthreads();
  float rs = rsqrtf((red[0] + red[1] + red[2] + red[3]) * (1.f / 1024.f) + 1e-6f);
  for (int c = tid; c < 1024; c += 256)
    qn[(size_t)s * 1024 + c] = f2bf(row[c] * rs * qw[c]);

  ss = 0.f;
  for (int c = tid; c < 896; c += 256) { float v = row[1024 + c]; ss += v * v; }
  ss += __shfl_xor(ss, 32); ss += __shfl_xor(ss, 16); ss += __shfl_xor(ss, 8);
  ss += __shfl_xor(ss, 4);  ss += __shfl_xor(ss, 2);  ss += __shfl_xor(ss, 1);
  __syncthreads();
  if ((tid & 63) == 0) red[tid >> 6] = ss;
  __syncthreads();
  rs = rsqrtf((red[0] + red[1] + red[2] + red[3]) * (1.f / 896.f) + 1e-6f);
  for (int c = tid; c < 896; c += 256)
    ckvn[(size_t)s * 896 + c] = f2bf(row[1024 + c] * rs * kvw[c]);

  if (tid < 64) {
    int d = tid;
    float x = row[1920 + d];
    float part = (d < 32) ? -row[1920 + d + 32] : row[1920 + d - 32];
    float v = x * cosp[(size_t)s * 64 + d] + part * sinp[(size_t)s * 64 + d];
    kr[(size_t)s * 64 + d] = f2bf(v);
  }
}

// ---------------- Q post: RoPE + SCALE -> bf16 ------------------------------
__global__ __launch_bounds__(256) void q_post(const float* __restrict__ Qf,
                                              const float* __restrict__ cosp,
                                              const float* __restrict__ sinp,
                                              unsigned short* __restrict__ Qb) {
  size_t idx = (size_t)blockIdx.x * 256 + threadIdx.x;
  int s = (int)(idx >> 12);
  int within = (int)(idx & 127);
  float v;
  if (within < 64) {
    v = Qf[idx];
  } else {
    int d = within - 64;
    float x = Qf[idx];
    float part = (d < 32) ? -Qf[idx + 32] : Qf[idx - 32];
    v = x * cosp[(size_t)s * 64 + d] + part * sinp[(size_t)s * 64 + d];
  }
  Qb[idx] = f2bf(v * 0.125f);
}

// ---------------- KV post: Kb=[k_nope|k_rope], Vt = V^T ---------------------
__global__ __launch_bounds__(256) void kv_post(const float* __restrict__ KVf,
                                               const unsigned short* __restrict__ kr,
                                               unsigned short* __restrict__ Kb,
                                               unsigned short* __restrict__ Vt) {
  __shared__ float lT[64 * 65];
  const int s0 = blockIdx.x * 64, h = blockIdx.y, tid = threadIdx.x;
  for (int idx = tid; idx < 4096; idx += 256) {
    int r = idx >> 6, c = idx & 63;
    size_t base = (size_t)(s0 + r) * 4096 + h * 128;
    Kb[base + c] = f2bf(KVf[base + c]);
    Kb[base + 64 + c] = kr[(size_t)(s0 + r) * 64 + c];
    lT[r * 65 + c] = KVf[base + 64 + c];
  }
  __syncthreads();
  for (int idx = tid; idx < 4096; idx += 256) {
    int d = idx >> 6, c = idx & 63;
    Vt[((size_t)h * 64 + d) * 2048 + s0 + c] = f2bf(lT[c * 65 + d]);
  }
}

// ---------------- flash attention (causal, swizzled LDS) --------------------
// grid (NH, S/64); q0 reversed so heavy blocks dispatch first (LPT).
// LDS swizzle: 16B-chunk index XOR (row&7); gload_lds writes linearly so the
// swizzle is applied by XOR-ing the per-lane GLOBAL source column (m173), and
// the same XOR on every ds_read address. lP padded to 72 elem rows instead.
__global__ __launch_bounds__(256) void flash_attn(const unsigned short* __restrict__ Qb,
                                                  const unsigned short* __restrict__ Kb,
                                                  const unsigned short* __restrict__ Vt,
                                                  unsigned short* __restrict__ Ao) {
  __shared__ unsigned short lK[64 * 128];
  __shared__ unsigned short lV[64 * 64];
  __shared__ unsigned short lP[64 * 72];
  const int tid = threadIdx.x, lane = tid & 63, wv = tid >> 6;
  const int h = blockIdx.x;
  const int q0 = ((int)gridDim.y - 1 - (int)blockIdx.y) * 64;

  bf16x8 qf[4];
  {
    const unsigned short* qrow = Qb + (size_t)(q0 + wv * 16 + (lane & 15)) * 4096 + h * 128;
#pragma unroll
    for (int ks = 0; ks < 4; ++ks)
      qf[ks] = *reinterpret_cast<const bf16x8*>(qrow + ks * 32 + (lane >> 4) * 8);
  }

  f32x4 o_acc[4] = {};
  float mrow[4] = {-1e30f, -1e30f, -1e30f, -1e30f};
  float lrow[4] = {};

  // staging geometry (constant per lane)
  const int rk = wv * 4 + (lane >> 4);                       // K row per instr group
  const int ckx = (((lane & 15) ^ (rk & 7)) * 8);            // swizzled K src col
  const int rv = wv * 8 + (lane >> 3);                       // V row per instr group
  const int cvx = ((((lane & 7) ^ ((lane >> 3) & 7))) * 8);  // swizzled V src col
  const int swz = lane & 7;                                  // read-side row&7

  for (int j0 = 0; j0 <= q0; j0 += 64) {
#pragma unroll
    for (int i = 0; i < 4; ++i)
      gload_lds16(Kb + (size_t)(j0 + i * 16 + rk) * 4096 + h * 128 + ckx,
                  &lK[(i * 16 + wv * 4) * 128]);
#pragma unroll
    for (int i = 0; i < 2; ++i)
      gload_lds16(Vt + ((size_t)h * 64 + i * 32 + rv) * 2048 + j0 + cvx,
                  &lV[(i * 32 + wv * 8) * 64]);
    __syncthreads();

    f32x4 s_acc[4] = {};
    __builtin_amdgcn_s_setprio(1);
#pragma unroll
    for (int n = 0; n < 4; ++n)
#pragma unroll
      for (int ks = 0; ks < 4; ++ks) {
        bf16x8 kf = *reinterpret_cast<const bf16x8*>(
            &lK[(n * 16 + (lane & 15)) * 128 + (((ks * 4 + (lane >> 4)) ^ swz)) * 8]);
        s_acc[n] = __builtin_amdgcn_mfma_f32_16x16x32_bf16(qf[ks], kf, s_acc[n], 0, 0, 0);
      }
    __builtin_amdgcn_s_setprio(0);

    if (j0 == q0) {  // diagonal block: causal mask
#pragma unroll
      for (int n = 0; n < 4; ++n)
#pragma unroll
        for (int r = 0; r < 4; ++r) {
          int qr = q0 + wv * 16 + (lane >> 4) * 4 + r;
          int kc = j0 + n * 16 + (lane & 15);
          if (kc > qr) s_acc[n][r] = -1e30f;
        }
    }

#pragma unroll
    for (int r = 0; r < 4; ++r) {
      float mx = fmaxf(fmaxf(s_acc[0][r], s_acc[1][r]), fmaxf(s_acc[2][r], s_acc[3][r]));
      mx = fmaxf(mx, __shfl_xor(mx, 1));
      mx = fmaxf(mx, __shfl_xor(mx, 2));
      mx = fmaxf(mx, __shfl_xor(mx, 4));
      mx = fmaxf(mx, __shfl_xor(mx, 8));
      float mn = fmaxf(mrow[r], mx);
      float sf = __expf(mrow[r] - mn);
      mrow[r] = mn;
      lrow[r] *= sf;
      o_acc[0][r] *= sf; o_acc[1][r] *= sf; o_acc[2][r] *= sf; o_acc[3][r] *= sf;
      float ps = 0.f;
#pragma unroll
      for (int n = 0; n < 4; ++n) {
        float p = __expf(s_acc[n][r] - mn);
        ps += p;
        lP[(wv * 16 + (lane >> 4) * 4 + r) * 72 + n * 16 + (lane & 15)] = f2bf(p);
      }
      ps += __shfl_xor(ps, 1); ps += __shfl_xor(ps, 2);
      ps += __shfl_xor(ps, 4); ps += __shfl_xor(ps, 8);
      lrow[r] += ps;
    }
    __syncthreads();  // lP visible to all (each wave reads only its own rows,
                      // but keep write->read ordered with lV reuse below)

    __builtin_amdgcn_s_setprio(1);
#pragma unroll
    for (int ks = 0; ks < 2; ++ks) {
      bf16x8 pa = *reinterpret_cast<const bf16x8*>(
          &lP[(wv * 16 + (lane & 15)) * 72 + ks * 32 + (lane >> 4) * 8]);
#pragma unroll
      for (int n = 0; n < 4; ++n) {
        bf16x8 vb = *reinterpret_cast<const bf16x8*>(
            &lV[(n * 16 + (lane & 15)) * 64 + (((ks * 4 + (lane >> 4)) ^ swz)) * 8]);
        o_acc[n] = __builtin_amdgcn_mfma_f32_16x16x32_bf16(pa, vb, o_acc[n], 0, 0, 0);
      }
    }
    __builtin_amdgcn_s_setprio(0);
    __syncthreads();
  }

#pragma unroll
  for (int r = 0; r < 4; ++r) {
    float inv = 1.f / lrow[r];
#pragma unroll
    for (int n = 0; n < 4; ++n) {
      float o = o_acc[n][r] * inv;
      Ao[(size_t)(q0 + wv * 16 + (lane >> 4) * 4 + r) * 2048 + h * 64 + n * 16 + (lane & 15)] =
          f2bf(o);
    }
  }
}

// ---------------------------------------------------------------------------
extern "C" void kernel_launch(void* const* d_in, const int* in_sizes, int n_in,
                              void* d_out, int out_size, void* d_ws, size_t ws_size,
                              hipStream_t stream) {
  const float* hs   = (const float*)d_in[0];
  const float* cosp = (const float*)d_in[1];
  const float* sinp = (const float*)d_in[2];
  const float* qaw  = (const float*)d_in[3];
  const float* qaln = (const float*)d_in[4];
  const float* qbwf = (const float*)d_in[5];
  const float* kvaw = (const float*)d_in[6];
  const float* kvln = (const float*)d_in[7];
  const float* kvbwf= (const float*)d_in[8];
  const float* owf  = (const float*)d_in[9];
  float* out = (float*)d_out;
  char* ws = (char*)d_ws;
  const size_t MB = 1u << 20;

  unsigned short* W1b  = (unsigned short*)(ws + 0);        // 8 MB   [dead after gemm1]
  unsigned short* Ao   = (unsigned short*)(ws + 0);        // 8 MB   (flash out)
  unsigned short* qbw  = (unsigned short*)(ws + 8 * MB);   // 8 MB   [dead after gemm2a]
  unsigned short* Vt   = (unsigned short*)(ws + 8 * MB);   // 8 MB   (kv_post out)
  unsigned short* kvbw = (unsigned short*)(ws + 16 * MB);  // 7 MB
  unsigned short* owb  = (unsigned short*)(ws + 23 * MB);  // 8 MB
  unsigned short* hsb  = (unsigned short*)(ws + 31 * MB);  // 8 MB   [dead after gemm1]
  unsigned short* Qb   = (unsigned short*)(ws + 31 * MB);  // 16 MB  (q_post out)
  float*          C1   = (float*)(ws + 39 * MB);           // 16 MB  [dead after rmsnorm]
  unsigned short* Kb   = (unsigned short*)(ws + 47 * MB);  // 16 MB  (kv_post out)
  unsigned short* qln  = (unsigned short*)(ws + 55 * MB);  // 4 MB   [dead after gemm2a]
  unsigned short* ckvn = (unsigned short*)(ws + 59 * MB);  // 3.5 MB [dead after gemm2b]
  unsigned short* kr   = (unsigned short*)(ws + 63 * MB);  // 0.25 MB
  float*          Qf   = (float*)(ws + 64 * MB);           // 32 MB
  float*          KVf  = (float*)(ws + 96 * MB);           // 32 MB
  (void)ws_size; (void)in_sizes; (void)n_in; (void)out_size;

  auto cgrid = [](size_t n) { return dim3((unsigned)((n / 4 + 255) / 256)); };

  cvt_pad<<<cgrid((size_t)1024 * 2048), 256, 0, stream>>>(qaw, W1b, (size_t)1024 * 2048, (size_t)1024 * 2048);
  cvt_pad<<<cgrid((size_t)1024 * 2048), 256, 0, stream>>>(kvaw, W1b + (size_t)1024 * 2048, (size_t)960 * 2048, (size_t)1024 * 2048);
  cvt_pad<<<cgrid((size_t)2048 * 2048), 256, 0, stream>>>(hs, hsb, (size_t)2048 * 2048, (size_t)2048 * 2048);
  cvt_pad<<<cgrid((size_t)4096 * 1024), 256, 0, stream>>>(qbwf, qbw, (size_t)4096 * 1024, (size_t)4096 * 1024);
  cvt_pad<<<cgrid((size_t)4096 * 896), 256, 0, stream>>>(kvbwf, kvbw, (size_t)4096 * 896, (size_t)4096 * 896);
  cvt_pad<<<cgrid((size_t)2048 * 2048), 256, 0, stream>>>(owf, owb, (size_t)2048 * 2048, (size_t)2048 * 2048);

  gemm_bt<<<dim3(16, 16), 256, 0, stream>>>(hsb, W1b, C1, 2048, 2048, 2048);
  rmsnorm_rope<<<2048, 256, 0, stream>>>(C1, qaln, kvln, cosp, sinp, qln, ckvn, kr);
  gemm_bt<<<dim3(32, 16), 256, 0, stream>>>(qln, qbw, Qf, 2048, 4096, 1024);
  gemm_bt<<<dim3(32, 16), 256, 0, stream>>>(ckvn, kvbw, KVf, 2048, 4096, 896);

  q_post<<<dim3((unsigned)(((size_t)2048 * 4096) / 256)), 256, 0, stream>>>(Qf, cosp, sinp, Qb);
  kv_post<<<dim3(32, 32), 256, 0, stream>>>(KVf, kr, Kb, Vt);

  flash_attn<<<dim3(32, 32), 256, 0, stream>>>(Qb, Kb, Vt, Ao);

  gemm_bt<<<dim3(16, 16), 256, 0, stream>>>(Ao, owb, out, 2048, 2048, 2048);
}